// Round 7
// baseline (213.904 us; speedup 1.0000x reference)
//
#include <hip/hip_runtime.h>
#include <hip/hip_bf16.h>
#include <math.h>

// ---------------------------------------------------------------------------
// FusionBlock_DenseAVInteractions — round 7
// fp32 in/out, bf16 MFMA internal. Factorized attention (exact):
//   out[q] = softmax_i(Sv)@Vv + softmax_j(Sa)@Va
//
// Round-6 post-mortem: removing launches was neutral -> launch overhead is
// NOT the bottleneck; the MLP GEMMs at 64x64 tiles (~81 TF measured in r2)
// are. Round-7: mlp1/mlp2 retiled to 128x128 (4 waves, 4x4 frags/wave,
// 16 MFMA per wave per k-step), mlp2 split-K=8 atomically into outp,
// mlp1 reads bf16 h0 produced by a tiny apply-only LN kernel (stats from
// proj's atomics). 7 launches.
// ---------------------------------------------------------------------------

typedef unsigned short ushort_t;
typedef __attribute__((ext_vector_type(8))) __bf16 bf16x8;
typedef __attribute__((ext_vector_type(4))) float f32x4;

#define DEVFN static __device__ __forceinline__

DEVFN float bf2f(ushort_t u) {
    return __uint_as_float(((unsigned int)u) << 16);
}
DEVFN ushort_t f2bf(float f) {
    unsigned int x = __float_as_uint(f);
    unsigned int r = x + 0x7FFFu + ((x >> 16) & 1u);  // RNE
    return (ushort_t)(r >> 16);
}
DEVFN void unpack8(uint4 dv, float* dst) {
    unsigned int ws[4] = {dv.x, dv.y, dv.z, dv.w};
#pragma unroll
    for (int i = 0; i < 4; i++) {
        dst[2 * i] = __uint_as_float(ws[i] << 16);
        dst[2 * i + 1] = __uint_as_float(ws[i] & 0xFFFF0000u);
    }
}

struct LNSeg {
    const float* x; const float* w; const float* b; ushort_t* out; int start;
};
struct TDesc { const float* in; ushort_t* out; int R, C, nx, start; };

// ---------------------------------------------------------------------------
// Prep: blocks [0,896) = 3 input LayerNorms (fp32 -> bf16);
//       blocks [896, 896+9728) = 5 weight transpose+casts;
//       block 0 zeroes the 1024-float stats buffer.
// ---------------------------------------------------------------------------
__global__ __launch_bounds__(256) void prep_kernel(LNSeg l0, LNSeg l1,
                                                   LNSeg l2, TDesc d0,
                                                   TDesc d1, TDesc d2,
                                                   TDesc d3, TDesc d4,
                                                   float* stats) {
    int id = blockIdx.x;
    int tid = threadIdx.x;
    if (id == 0) ((float4*)stats)[tid] = (float4){0.f, 0.f, 0.f, 0.f};

    if (id < 896) {
        const float *x, *w, *b; ushort_t* o; int start;
        if (id >= l2.start)      { x = l2.x; w = l2.w; b = l2.b; o = l2.out; start = l2.start; }
        else if (id >= l1.start) { x = l1.x; w = l1.w; b = l1.b; o = l1.out; start = l1.start; }
        else                     { x = l0.x; w = l0.w; b = l0.b; o = l0.out; start = 0; }
        int row = id - start;
        const float4* xr4 = (const float4*)(x + (size_t)row * 1024);
        float4 v4 = xr4[tid];
        float s = v4.x + v4.y + v4.z + v4.w;
        float ss = v4.x * v4.x + v4.y * v4.y + v4.z * v4.z + v4.w * v4.w;
#pragma unroll
        for (int off = 32; off > 0; off >>= 1) {
            s += __shfl_down(s, off);
            ss += __shfl_down(ss, off);
        }
        __shared__ float red[8];
        if ((tid & 63) == 0) {
            red[tid >> 6] = s;
            red[4 + (tid >> 6)] = ss;
        }
        __syncthreads();
        s = red[0] + red[1] + red[2] + red[3];
        ss = red[4] + red[5] + red[6] + red[7];
        float mean = s * (1.f / 1024.f);
        float var = ss * (1.f / 1024.f) - mean * mean;
        float rstd = rsqrtf(var + 1e-5f);
        const float4 w4 = ((const float4*)w)[tid];
        const float4 b4 = ((const float4*)b)[tid];
        union { ushort_t u[4]; uint2 v; } pk;
        pk.u[0] = f2bf((v4.x - mean) * rstd * w4.x + b4.x);
        pk.u[1] = f2bf((v4.y - mean) * rstd * w4.y + b4.y);
        pk.u[2] = f2bf((v4.z - mean) * rstd * w4.z + b4.z);
        pk.u[3] = f2bf((v4.w - mean) * rstd * w4.w + b4.w);
        *(uint2*)(o + (size_t)row * 1024 + tid * 4) = pk.v;
        return;
    }

    int t = id - 896;
    const float* in; ushort_t* out; int R, C, nx, start;
    if (t >= d4.start)      { in = d4.in; out = d4.out; R = d4.R; C = d4.C; nx = d4.nx; start = d4.start; }
    else if (t >= d3.start) { in = d3.in; out = d3.out; R = d3.R; C = d3.C; nx = d3.nx; start = d3.start; }
    else if (t >= d2.start) { in = d2.in; out = d2.out; R = d2.R; C = d2.C; nx = d2.nx; start = d2.start; }
    else if (t >= d1.start) { in = d1.in; out = d1.out; R = d1.R; C = d1.C; nx = d1.nx; start = d1.start; }
    else                    { in = d0.in; out = d0.out; R = d0.R; C = d0.C; nx = d0.nx; start = 0; }
    int tt = t - start;
    int bx = (tt % nx) * 32;
    int by = (tt / nx) * 32;
    __shared__ ushort_t tile[32 * 33];
    int r = tid >> 3, c4 = (tid & 7) * 4;
    float4 f = *(const float4*)(in + (size_t)(by + r) * C + bx + c4);
    ushort_t* tr = tile + r * 33 + c4;
    tr[0] = f2bf(f.x); tr[1] = f2bf(f.y); tr[2] = f2bf(f.z); tr[3] = f2bf(f.w);
    __syncthreads();
    int oc = tid >> 3, or4 = (tid & 7) * 4;
    union { ushort_t u[4]; uint2 v; } pk;
#pragma unroll
    for (int j = 0; j < 4; j++) pk.u[j] = tile[(or4 + j) * 33 + oc];
    *(uint2*)(out + (size_t)(bx + oc) * R + by + or4) = pk.v;
}

// ---------------------------------------------------------------------------
// 64x64 pipelined MFMA GEMM item (2x2 waves), bf16 out. For qkv.
// ---------------------------------------------------------------------------
DEVFN void gemm64_item(const ushort_t* __restrict__ A, int lda,
                       const ushort_t* __restrict__ B, int ldb,
                       ushort_t* __restrict__ C, int ldc, int K, int m0,
                       int n0, ushort_t* As, ushort_t* Bs) {
    constexpr int LS = 40;
    int tid = threadIdx.x;
    int wave = tid >> 6, lane = tid & 63;
    int wm = wave >> 1, wn = wave & 1;
    int quad = lane >> 4, l16 = lane & 15;

    f32x4 acc[2][2];
#pragma unroll
    for (int i = 0; i < 2; i++)
#pragma unroll
        for (int j = 0; j < 2; j++) acc[i][j] = (f32x4){0.f, 0.f, 0.f, 0.f};

    int r = tid >> 2, c = tid & 3;
    const ushort_t* Ap = A + (size_t)(m0 + r) * lda + c * 8;
    const ushort_t* Bp = B + (size_t)(n0 + r) * ldb + c * 8;
    uint4 ra = *(const uint4*)Ap;
    uint4 rb = *(const uint4*)Bp;

    for (int k0 = 0; k0 < K; k0 += 32) {
        *(uint4*)(&As[r * LS + c * 8]) = ra;
        *(uint4*)(&Bs[r * LS + c * 8]) = rb;
        __syncthreads();
        if (k0 + 32 < K) {
            ra = *(const uint4*)(Ap + k0 + 32);
            rb = *(const uint4*)(Bp + k0 + 32);
        }
        bf16x8 af[2], bfr[2];
#pragma unroll
        for (int i = 0; i < 2; i++)
            af[i] = *(const bf16x8*)(&As[(wm * 32 + i * 16 + l16) * LS + quad * 8]);
#pragma unroll
        for (int j = 0; j < 2; j++)
            bfr[j] = *(const bf16x8*)(&Bs[(wn * 32 + j * 16 + l16) * LS + quad * 8]);
#pragma unroll
        for (int i = 0; i < 2; i++)
#pragma unroll
            for (int j = 0; j < 2; j++)
                acc[i][j] = __builtin_amdgcn_mfma_f32_16x16x32_bf16(
                    af[i], bfr[j], acc[i][j], 0, 0, 0);
        __syncthreads();
    }

#pragma unroll
    for (int i = 0; i < 2; i++)
#pragma unroll
        for (int j = 0; j < 2; j++) {
            int col = n0 + wn * 32 + j * 16 + l16;
            int rbase = m0 + wm * 32 + i * 16 + quad * 4;
#pragma unroll
            for (int rr = 0; rr < 4; rr++)
                C[(size_t)(rbase + rr) * ldc + col] = f2bf(acc[i][j][rr]);
        }
}

struct GSeg {
    const ushort_t* A; const ushort_t* B; ushort_t* C;
    int lda, ldb, ldc, nx, start;
};
__global__ __launch_bounds__(256) void gemm64_multi(GSeg s0, GSeg s1, GSeg s2,
                                                    int K) {
    __shared__ ushort_t As[64 * 40];
    __shared__ ushort_t Bs[64 * 40];
    int id = blockIdx.x;
    GSeg s = (id >= s2.start) ? s2 : ((id >= s1.start) ? s1 : s0);
    int t = id - s.start;
    gemm64_item(s.A, s.lda, s.B, s.ldb, s.C, s.ldc, K, (t / s.nx) * 64,
                (t % s.nx) * 64, As, Bs);
}

// ---------------------------------------------------------------------------
// 128x128 pipelined MFMA GEMM core: 4 waves (2x2), each 64x64 = 4x4 frags,
// 16 MFMA per wave per k-step. EPI: 2 = +bias +GELU bf16; 5 = atomicAdd fp32.
// ---------------------------------------------------------------------------
template <int EPI, typename OutT>
DEVFN void gemm128_core(const ushort_t* __restrict__ A, int lda,
                        const ushort_t* __restrict__ B, int ldb,
                        OutT* __restrict__ C, int ldc,
                        const float* __restrict__ bias, int K, int m0, int n0,
                        ushort_t* As, ushort_t* Bs) {
    constexpr int LS = 40;
    int tid = threadIdx.x;
    int wave = tid >> 6, lane = tid & 63;
    int wm = wave >> 1, wn = wave & 1;
    int quad = lane >> 4, l16 = lane & 15;

    f32x4 acc[4][4];
#pragma unroll
    for (int i = 0; i < 4; i++)
#pragma unroll
        for (int j = 0; j < 4; j++) acc[i][j] = (f32x4){0.f, 0.f, 0.f, 0.f};

    int r = tid >> 1;            // 0..127
    int c = (tid & 1) * 16;      // element offset: 0 or 16
    const ushort_t* Ap = A + (size_t)(m0 + r) * lda + c;
    const ushort_t* Bp = B + (size_t)(n0 + r) * ldb + c;
    uint4 ra0 = *(const uint4*)Ap;
    uint4 ra1 = *(const uint4*)(Ap + 8);
    uint4 rb0 = *(const uint4*)Bp;
    uint4 rb1 = *(const uint4*)(Bp + 8);

    for (int k0 = 0; k0 < K; k0 += 32) {
        *(uint4*)(&As[r * LS + c]) = ra0;
        *(uint4*)(&As[r * LS + c + 8]) = ra1;
        *(uint4*)(&Bs[r * LS + c]) = rb0;
        *(uint4*)(&Bs[r * LS + c + 8]) = rb1;
        __syncthreads();
        if (k0 + 32 < K) {
            ra0 = *(const uint4*)(Ap + k0 + 32);
            ra1 = *(const uint4*)(Ap + k0 + 40);
            rb0 = *(const uint4*)(Bp + k0 + 32);
            rb1 = *(const uint4*)(Bp + k0 + 40);
        }
        bf16x8 af[4], bfr[4];
#pragma unroll
        for (int i = 0; i < 4; i++)
            af[i] = *(const bf16x8*)(&As[(wm * 64 + i * 16 + l16) * LS + quad * 8]);
#pragma unroll
        for (int j = 0; j < 4; j++)
            bfr[j] = *(const bf16x8*)(&Bs[(wn * 64 + j * 16 + l16) * LS + quad * 8]);
#pragma unroll
        for (int i = 0; i < 4; i++)
#pragma unroll
            for (int j = 0; j < 4; j++)
                acc[i][j] = __builtin_amdgcn_mfma_f32_16x16x32_bf16(
                    af[i], bfr[j], acc[i][j], 0, 0, 0);
        __syncthreads();
    }

#pragma unroll
    for (int i = 0; i < 4; i++)
#pragma unroll
        for (int j = 0; j < 4; j++) {
            int col = n0 + wn * 64 + j * 16 + l16;
            int rbase = m0 + wm * 64 + i * 16 + quad * 4;
            float bv = (EPI == 2) ? bias[col] : 0.f;
#pragma unroll
            for (int rr = 0; rr < 4; rr++) {
                int row = rbase + rr;
                float vv = acc[i][j][rr] + bv;
                if constexpr (EPI == 2) {
                    vv = 0.5f * vv * (1.f + erff(vv * 0.70710678118654752f));
                    C[(size_t)row * ldc + col] = (OutT)f2bf(vv);
                } else {
                    atomicAdd((float*)&C[(size_t)row * ldc + col], vv);
                }
            }
        }
}

// mlp1: g = gelu(h0 @ W1t^T + b1), grid (32, 4)
__global__ __launch_bounds__(256) void gemm_mlp1(
    const ushort_t* __restrict__ h0, const ushort_t* __restrict__ W1t,
    const float* __restrict__ b1, ushort_t* __restrict__ g) {
    __shared__ ushort_t As[128 * 40];
    __shared__ ushort_t Bs[128 * 40];
    gemm128_core<2, ushort_t>(h0, 1024, W1t, 1024, g, 4096, b1, 1024,
                              blockIdx.y * 128, blockIdx.x * 128, As, Bs);
}

// mlp2: split-K=8, atomicAdd into outp (pre-init to y+b2). grid (8, 4, 8)
__global__ __launch_bounds__(256) void gemm_mlp2(
    const ushort_t* __restrict__ g, const ushort_t* __restrict__ W2t,
    float* __restrict__ outp) {
    __shared__ ushort_t As[128 * 40];
    __shared__ ushort_t Bs[128 * 40];
    int z = blockIdx.z;
    gemm128_core<5, float>(g + z * 512, 4096, W2t + z * 512, 4096, outp, 1024,
                           nullptr, 512, blockIdx.y * 128, blockIdx.x * 128,
                           As, Bs);
}

// ---------------------------------------------------------------------------
// proj: y = attnout @ Wproj + bproj + xmm (fp32), K=256. Also outp = y + b2
// (init for mlp2 atomics) and per-row sum/sumsq atomics into stats[1024].
// grid (16, 8).
// ---------------------------------------------------------------------------
__global__ __launch_bounds__(256) void gemm_proj(
    const ushort_t* __restrict__ A, const ushort_t* __restrict__ Bt,
    const float* __restrict__ bproj, const float* __restrict__ xmm,
    const float* __restrict__ b2, float* __restrict__ y,
    float* __restrict__ outp, float* __restrict__ stats) {
    constexpr int LS = 40;
    __shared__ ushort_t As[64 * LS];
    __shared__ ushort_t Bs[64 * LS];
    int tid = threadIdx.x;
    int wave = tid >> 6, lane = tid & 63;
    int wm = wave >> 1, wn = wave & 1;
    int quad = lane >> 4, l16 = lane & 15;
    int m0 = blockIdx.y * 64, n0 = blockIdx.x * 64;

    f32x4 acc[2][2];
#pragma unroll
    for (int i = 0; i < 2; i++)
#pragma unroll
        for (int j = 0; j < 2; j++) acc[i][j] = (f32x4){0.f, 0.f, 0.f, 0.f};

    int r = tid >> 2, c = tid & 3;
    const ushort_t* Ap = A + (size_t)(m0 + r) * 256 + c * 8;
    const ushort_t* Bp = Bt + (size_t)(n0 + r) * 256 + c * 8;
    uint4 ra = *(const uint4*)Ap;
    uint4 rb = *(const uint4*)Bp;

    for (int k0 = 0; k0 < 256; k0 += 32) {
        *(uint4*)(&As[r * LS + c * 8]) = ra;
        *(uint4*)(&Bs[r * LS + c * 8]) = rb;
        __syncthreads();
        if (k0 + 32 < 256) {
            ra = *(const uint4*)(Ap + k0 + 32);
            rb = *(const uint4*)(Bp + k0 + 32);
        }
        bf16x8 af[2], bfr[2];
#pragma unroll
        for (int i = 0; i < 2; i++)
            af[i] = *(const bf16x8*)(&As[(wm * 32 + i * 16 + l16) * LS + quad * 8]);
#pragma unroll
        for (int j = 0; j < 2; j++)
            bfr[j] = *(const bf16x8*)(&Bs[(wn * 32 + j * 16 + l16) * LS + quad * 8]);
#pragma unroll
        for (int i = 0; i < 2; i++)
#pragma unroll
            for (int j = 0; j < 2; j++)
                acc[i][j] = __builtin_amdgcn_mfma_f32_16x16x32_bf16(
                    af[i], bfr[j], acc[i][j], 0, 0, 0);
        __syncthreads();
    }

    float rs[2][4] = {{0.f, 0.f, 0.f, 0.f}, {0.f, 0.f, 0.f, 0.f}};
    float rq[2][4] = {{0.f, 0.f, 0.f, 0.f}, {0.f, 0.f, 0.f, 0.f}};
#pragma unroll
    for (int i = 0; i < 2; i++)
#pragma unroll
        for (int j = 0; j < 2; j++) {
            int col = n0 + wn * 32 + j * 16 + l16;
            int rbase = m0 + wm * 32 + i * 16 + quad * 4;
            float bv = bproj[col];
            float b2v = b2[col];
#pragma unroll
            for (int rr = 0; rr < 4; rr++) {
                int row = rbase + rr;
                float vv = acc[i][j][rr] + bv + xmm[(size_t)row * 1024 + col];
                y[(size_t)row * 1024 + col] = vv;
                outp[(size_t)row * 1024 + col] = vv + b2v;
                rs[i][rr] += vv;
                rq[i][rr] += vv * vv;
            }
        }
#pragma unroll
    for (int i = 0; i < 2; i++)
#pragma unroll
        for (int rr = 0; rr < 4; rr++) {
            float s = rs[i][rr], q = rq[i][rr];
            s += __shfl_xor(s, 1); q += __shfl_xor(q, 1);
            s += __shfl_xor(s, 2); q += __shfl_xor(q, 2);
            s += __shfl_xor(s, 4); q += __shfl_xor(q, 4);
            s += __shfl_xor(s, 8); q += __shfl_xor(q, 8);
            if (l16 == 0) {
                int row = m0 + wm * 32 + i * 16 + quad * 4 + rr;
                atomicAdd(&stats[row], s);
                atomicAdd(&stats[512 + row], q);
            }
        }
}

// ---------------------------------------------------------------------------
// ln_apply: h0[row] = LN(y[row]) using precomputed stats. Apply-only.
// ---------------------------------------------------------------------------
__global__ __launch_bounds__(256) void ln_apply(
    const float* __restrict__ y, const float* __restrict__ stats,
    const float* __restrict__ w, const float* __restrict__ b,
    ushort_t* __restrict__ h0) {
    int row = blockIdx.x, tid = threadIdx.x;
    float s = stats[row], ss = stats[512 + row];
    float mean = s * (1.f / 1024.f);
    float rstd = rsqrtf(ss * (1.f / 1024.f) - mean * mean + 1e-5f);
    float4 v4 = ((const float4*)(y + (size_t)row * 1024))[tid];
    float4 w4 = ((const float4*)w)[tid];
    float4 b4 = ((const float4*)b)[tid];
    union { ushort_t u[4]; uint2 v; } pk;
    pk.u[0] = f2bf((v4.x - mean) * rstd * w4.x + b4.x);
    pk.u[1] = f2bf((v4.y - mean) * rstd * w4.y + b4.y);
    pk.u[2] = f2bf((v4.z - mean) * rstd * w4.z + b4.z);
    pk.u[3] = f2bf((v4.w - mean) * rstd * w4.w + b4.w);
    *(uint2*)(h0 + (size_t)row * 1024 + tid * 4) = pk.v;
}

// ---------------------------------------------------------------------------
// Factorized attention. Block = 256 threads: 64 q-rows x 4 dim-groups.
// grid (B*H=32, 4 q-chunks). Single-pass softmax (|s| bounded, no overflow).
// ---------------------------------------------------------------------------
__global__ __launch_bounds__(256) void attn_kernel(
    const ushort_t* __restrict__ q, const ushort_t* __restrict__ kvv,
    const ushort_t* __restrict__ kva, ushort_t* __restrict__ out) {
    int bh = blockIdx.x;
    int b = bh >> 4, h = bh & 15;
    int tid = threadIdx.x;

    __shared__ float Kv[64][16], Vv[64][16], Ka[128][16], Va[128][16];
    {
        int row = tid >> 2, seg = (tid >> 1) & 1, half = tid & 1;
        const ushort_t* src =
            kvv + (size_t)(b * 64 + row) * 512 + seg * 256 + h * 16 + half * 8;
        float* dst = (seg ? Vv[row] : Kv[row]) + half * 8;
        unpack8(*(const uint4*)src, dst);
    }
#pragma unroll
    for (int t2 = 0; t2 < 2; t2++) {
        int t = tid + t2 * 256;
        int row = t >> 2, seg = (t >> 1) & 1, half = t & 1;
        const ushort_t* src =
            kva + (size_t)(b * 128 + row) * 512 + seg * 256 + h * 16 + half * 8;
        float* dst = (seg ? Va[row] : Ka[row]) + half * 8;
        unpack8(*(const uint4*)src, dst);
    }
    __syncthreads();

    int qlocal = tid >> 2;
    int dg = tid & 3;
    int qrow = blockIdx.y * 64 + qlocal;
    const ushort_t* qp = q + (size_t)(b * 256 + qrow) * 256 + h * 16 + dg * 4;
    uint2 qu = *(const uint2*)qp;
    float4 qv;
    qv.x = __uint_as_float(qu.x << 16) * 0.125f;
    qv.y = __uint_as_float(qu.x & 0xFFFF0000u) * 0.125f;
    qv.z = __uint_as_float(qu.y << 16) * 0.125f;
    qv.w = __uint_as_float(qu.y & 0xFFFF0000u) * 0.125f;

    const float4* Kv4 = (const float4*)Kv;
    const float4* Vv4 = (const float4*)Vv;
    const float4* Ka4 = (const float4*)Ka;
    const float4* Va4 = (const float4*)Va;

    float4 ov = {0.f, 0.f, 0.f, 0.f};
    float den = 0.f;
#pragma unroll 8
    for (int i = 0; i < 64; i++) {
        float4 kk = Kv4[i * 4 + dg];
        float part = qv.x * kk.x + qv.y * kk.y + qv.z * kk.z + qv.w * kk.w;
        part += __shfl_xor(part, 1);
        part += __shfl_xor(part, 2);
        float pe = __expf(part);
        den += pe;
        float4 vv = Vv4[i * 4 + dg];
        ov.x += pe * vv.x; ov.y += pe * vv.y;
        ov.z += pe * vv.z; ov.w += pe * vv.w;
    }
    float4 oa = {0.f, 0.f, 0.f, 0.f};
    float dena = 0.f;
#pragma unroll 8
    for (int i = 0; i < 128; i++) {
        float4 kk = Ka4[i * 4 + dg];
        float part = qv.x * kk.x + qv.y * kk.y + qv.z * kk.z + qv.w * kk.w;
        part += __shfl_xor(part, 1);
        part += __shfl_xor(part, 2);
        float pe = __expf(part);
        dena += pe;
        float4 vv = Va4[i * 4 + dg];
        oa.x += pe * vv.x; oa.y += pe * vv.y;
        oa.z += pe * vv.z; oa.w += pe * vv.w;
    }

    float rv = 1.f / den, ra = 1.f / dena;
    union { ushort_t u[4]; uint2 v; } pk;
    pk.u[0] = f2bf(ov.x * rv + oa.x * ra);
    pk.u[1] = f2bf(ov.y * rv + oa.y * ra);
    pk.u[2] = f2bf(ov.z * rv + oa.z * ra);
    pk.u[3] = f2bf(ov.w * rv + oa.w * ra);
    *(uint2*)(out + (size_t)(b * 256 + qrow) * 256 + h * 16 + dg * 4) = pk.v;
}

// ---------------------------------------------------------------------------
extern "C" void kernel_launch(void* const* d_in, const int* in_sizes, int n_in,
                              void* d_out, int out_size, void* d_ws,
                              size_t ws_size, hipStream_t stream) {
    const float* xmm = (const float*)d_in[0];
    const float* xv = (const float*)d_in[1];
    const float* xa = (const float*)d_in[2];
    const float* ln_mm_w = (const float*)d_in[3];
    const float* ln_mm_b = (const float*)d_in[4];
    const float* ln_v_w = (const float*)d_in[5];
    const float* ln_v_b = (const float*)d_in[6];
    const float* ln_a_w = (const float*)d_in[7];
    const float* ln_a_b = (const float*)d_in[8];
    const float* Wq = (const float*)d_in[9];
    const float* Wkv = (const float*)d_in[10];
    const float* Wproj = (const float*)d_in[11];
    const float* bproj = (const float*)d_in[12];
    const float* ln_mlp_w = (const float*)d_in[13];
    const float* ln_mlp_b = (const float*)d_in[14];
    const float* W1 = (const float*)d_in[15];
    const float* b1 = (const float*)d_in[16];
    const float* W2 = (const float*)d_in[17];
    const float* b2 = (const float*)d_in[18];
    float* outp = (float*)d_out;

    char* w = (char*)d_ws;
    ushort_t* xmmN = (ushort_t*)w;    w += 512 * 1024 * 2;
    ushort_t* xvN = (ushort_t*)w;     w += 128 * 1024 * 2;
    ushort_t* xaN = (ushort_t*)w;     w += 256 * 1024 * 2;
    ushort_t* Wqt = (ushort_t*)w;     w += 256 * 1024 * 2;
    ushort_t* Wkvt = (ushort_t*)w;    w += 512 * 2048 * 2;
    ushort_t* Wprojt = (ushort_t*)w;  w += 1024 * 256 * 2;
    ushort_t* W1t = (ushort_t*)w;     w += 4096 * 1024 * 2;
    ushort_t* W2t = (ushort_t*)w;     w += 1024 * 4096 * 2;
    ushort_t* qout = (ushort_t*)w;    w += 512 * 256 * 2;
    ushort_t* kvvb = (ushort_t*)w;    w += 128 * 512 * 2;
    ushort_t* kvab = (ushort_t*)w;    w += 256 * 512 * 2;
    ushort_t* attnout = (ushort_t*)w; w += 512 * 256 * 2;
    float* y = (float*)w;             w += 512 * 1024 * 4;
    ushort_t* h0 = (ushort_t*)w;      w += 512 * 1024 * 2;
    ushort_t* g = (ushort_t*)w;       w += 512 * 4096 * 2;
    float* stats = (float*)w;         w += 1024 * 4;

    // 1) prep: 3 LNs + 5 transposes + zero stats
    LNSeg L0{xmm, ln_mm_w, ln_mm_b, xmmN, 0};
    LNSeg L1{xv, ln_v_w, ln_v_b, xvN, 512};
    LNSeg L2{xa, ln_a_w, ln_a_b, xaN, 640};
    TDesc T0{Wq, Wqt, 1024, 256, 8, 0};
    TDesc T1{Wkv, Wkvt, 2048, 512, 16, 256};
    TDesc T2{Wproj, Wprojt, 256, 1024, 32, 1280};
    TDesc T3{W1, W1t, 1024, 4096, 128, 1536};
    TDesc T4{W2, W2t, 4096, 1024, 32, 5632};
    prep_kernel<<<896 + 9728, 256, 0, stream>>>(L0, L1, L2, T0, T1, T2, T3,
                                                T4, stats);

    // 2) q / kv_v / kv_a projections (80 blocks)
    GSeg G0{xmmN, Wqt, qout, 1024, 1024, 256, 4, 0};
    GSeg G1{xvN, Wkvt, kvvb, 1024, 2048, 512, 8, 32};
    GSeg G2{xaN, Wkvt + 1024, kvab, 1024, 2048, 512, 8, 48};
    gemm64_multi<<<80, 256, 0, stream>>>(G0, G1, G2, 1024);

    // 3) factorized attention
    attn_kernel<<<dim3(32, 4), 256, 0, stream>>>(qout, kvvb, kvab, attnout);

    // 4) proj (+ outp init + LN stats)
    gemm_proj<<<dim3(16, 8), 256, 0, stream>>>(attnout, Wprojt, bproj, xmm,
                                               b2, y, outp, stats);

    // 5) h0 = LN(y) via precomputed stats (apply-only)
    ln_apply<<<512, 256, 0, stream>>>(y, stats, ln_mlp_w, ln_mlp_b, h0);

    // 6) mlp1: g = gelu(h0 @ W1 + b1), 128x128 tiles
    gemm_mlp1<<<dim3(32, 4), 256, 0, stream>>>(h0, W1t, b1, g);

    // 7) mlp2: split-K=8, 128x128 tiles, atomic accumulate into outp
    gemm_mlp2<<<dim3(8, 4, 8), 256, 0, stream>>>(g, W2t, outp);

    (void)in_sizes; (void)n_in; (void)out_size; (void)ws_size;
}

// Round 8
// 207.570 us; speedup vs baseline: 1.0305x; 1.0305x over previous
//
#include <hip/hip_runtime.h>
#include <hip/hip_bf16.h>
#include <math.h>

// ---------------------------------------------------------------------------
// FusionBlock_DenseAVInteractions — round 8
// fp32 in/out, bf16 MFMA internal. Factorized attention (exact):
//   out[q] = softmax_i(Sv)@Vv + softmax_j(Sa)@Va
//
// Round-7 post-mortem: LDS-staged barrier-locked GEMMs cost ~4.7x the
// theoretical step time at any tile size (~70 TF); with 9.7 GFLOP total
// that IS the 200-us budget. Round-8: barrier-free LDS-free wave GEMM —
// 1 wave per block, MFMA fragments loaded directly global->register
// (fragment = contiguous 16B dwordx4 per lane), register prefetch, no
// __syncthreads. Hundreds of independent blocks spread over all CUs.
// ---------------------------------------------------------------------------

typedef unsigned short ushort_t;
typedef __attribute__((ext_vector_type(8))) __bf16 bf16x8;
typedef __attribute__((ext_vector_type(4))) float f32x4;

#define DEVFN static __device__ __forceinline__

DEVFN float bf2f(ushort_t u) {
    return __uint_as_float(((unsigned int)u) << 16);
}
DEVFN ushort_t f2bf(float f) {
    unsigned int x = __float_as_uint(f);
    unsigned int r = x + 0x7FFFu + ((x >> 16) & 1u);  // RNE
    return (ushort_t)(r >> 16);
}
DEVFN bf16x8 asbf8(uint4 v) {
    union { uint4 u; bf16x8 b; } c;
    c.u = v;
    return c.b;
}
DEVFN void unpack8(uint4 dv, float* dst) {
    unsigned int ws[4] = {dv.x, dv.y, dv.z, dv.w};
#pragma unroll
    for (int i = 0; i < 4; i++) {
        dst[2 * i] = __uint_as_float(ws[i] << 16);
        dst[2 * i + 1] = __uint_as_float(ws[i] & 0xFFFF0000u);
    }
}

// ---------------------------------------------------------------------------
// Wave GEMM core: one 64-lane wave computes an (TM*16) x 64 tile of
// C = A[M,K] @ Bt[N,K]^T entirely in registers. A/B fragments are loaded
// straight from global: lane(l16,quad) holds A[m0+i*16+l16][k0+quad*8 ..+7]
// (16 contiguous bytes). Next k-step prefetched into registers. No LDS.
// ---------------------------------------------------------------------------
template <int TM, int K>
DEVFN void wave_acc(const ushort_t* __restrict__ A, int lda,
                    const ushort_t* __restrict__ B, int ldb, int m0, int n0,
                    int lane, f32x4 (&acc)[TM][4]) {
    int quad = lane >> 4, l16 = lane & 15;
    const ushort_t* Ap = A + (size_t)(m0 + l16) * lda + quad * 8;
    const ushort_t* Bp = B + (size_t)(n0 + l16) * ldb + quad * 8;

    uint4 ra[TM], rb[4];
#pragma unroll
    for (int i = 0; i < TM; i++)
        ra[i] = *(const uint4*)(Ap + (size_t)i * 16 * lda);
#pragma unroll
    for (int j = 0; j < 4; j++)
        rb[j] = *(const uint4*)(Bp + (size_t)j * 16 * ldb);

#pragma unroll 2
    for (int k0 = 0; k0 < K; k0 += 32) {
        uint4 na[TM], nb[4];
        if (k0 + 32 < K) {
#pragma unroll
            for (int i = 0; i < TM; i++)
                na[i] = *(const uint4*)(Ap + (size_t)i * 16 * lda + k0 + 32);
#pragma unroll
            for (int j = 0; j < 4; j++)
                nb[j] = *(const uint4*)(Bp + (size_t)j * 16 * ldb + k0 + 32);
        }
#pragma unroll
        for (int i = 0; i < TM; i++) {
            bf16x8 af = asbf8(ra[i]);
#pragma unroll
            for (int j = 0; j < 4; j++)
                acc[i][j] = __builtin_amdgcn_mfma_f32_16x16x32_bf16(
                    af, asbf8(rb[j]), acc[i][j], 0, 0, 0);
        }
        if (k0 + 32 < K) {
#pragma unroll
            for (int i = 0; i < TM; i++) ra[i] = na[i];
#pragma unroll
            for (int j = 0; j < 4; j++) rb[j] = nb[j];
        }
    }
}

// ---------------------------------------------------------------------------
// qkv: q = xmmN@Wqt^T [512,256]; kv_v = xvN@Wkvt^T [128,512];
//      kv_a = xaN@(Wkvt+1024)^T [256,512]. 32x64 tiles, 160 blocks x 64 thr.
// ---------------------------------------------------------------------------
__global__ __launch_bounds__(64) void qkv_kernel(
    const ushort_t* __restrict__ xmmN, const ushort_t* __restrict__ xvN,
    const ushort_t* __restrict__ xaN, const ushort_t* __restrict__ Wqt,
    const ushort_t* __restrict__ Wkvt, ushort_t* __restrict__ qout,
    ushort_t* __restrict__ kvvb, ushort_t* __restrict__ kvab) {
    int id = blockIdx.x;
    int lane = threadIdx.x;
    const ushort_t *A, *B;
    ushort_t* C;
    int lda, ldb, ldc, m0, n0;
    if (id < 64) {            // q
        A = xmmN; B = Wqt; C = qout; lda = 1024; ldb = 1024; ldc = 256;
        m0 = (id >> 2) * 32; n0 = (id & 3) * 64;
    } else if (id < 96) {     // kv_v
        int t = id - 64;
        A = xvN; B = Wkvt; C = kvvb; lda = 1024; ldb = 2048; ldc = 512;
        m0 = (t >> 3) * 32; n0 = (t & 7) * 64;
    } else {                  // kv_a
        int t = id - 96;
        A = xaN; B = Wkvt + 1024; C = kvab; lda = 1024; ldb = 2048; ldc = 512;
        m0 = (t >> 3) * 32; n0 = (t & 7) * 64;
    }
    f32x4 acc[2][4];
#pragma unroll
    for (int i = 0; i < 2; i++)
#pragma unroll
        for (int j = 0; j < 4; j++) acc[i][j] = (f32x4){0.f, 0.f, 0.f, 0.f};
    wave_acc<2, 1024>(A, lda, B, ldb, m0, n0, lane, acc);

    int quad = lane >> 4, l16 = lane & 15;
#pragma unroll
    for (int i = 0; i < 2; i++)
#pragma unroll
        for (int j = 0; j < 4; j++) {
            int col = n0 + j * 16 + l16;
            int rbase = m0 + i * 16 + quad * 4;
#pragma unroll
            for (int rr = 0; rr < 4; rr++)
                C[(size_t)(rbase + rr) * ldc + col] = f2bf(acc[i][j][rr]);
        }
}

// ---------------------------------------------------------------------------
// proj: y = attnout@Wprojt^T + bproj + xmm (fp32), outp = y + b2,
// per-row sum/sumsq atomics into stats. 32x64 tiles, 256 blocks, K=256.
// ---------------------------------------------------------------------------
__global__ __launch_bounds__(64) void proj_kernel(
    const ushort_t* __restrict__ attnout, const ushort_t* __restrict__ Wprojt,
    const float* __restrict__ bproj, const float* __restrict__ xmm,
    const float* __restrict__ b2, float* __restrict__ y,
    float* __restrict__ outp, float* __restrict__ stats) {
    int id = blockIdx.x;
    int lane = threadIdx.x;
    int m0 = (id >> 4) * 32, n0 = (id & 15) * 64;
    f32x4 acc[2][4];
#pragma unroll
    for (int i = 0; i < 2; i++)
#pragma unroll
        for (int j = 0; j < 4; j++) acc[i][j] = (f32x4){0.f, 0.f, 0.f, 0.f};
    wave_acc<2, 256>(attnout, 256, Wprojt, 256, m0, n0, lane, acc);

    int quad = lane >> 4, l16 = lane & 15;
    float rs[2][4] = {{0.f, 0.f, 0.f, 0.f}, {0.f, 0.f, 0.f, 0.f}};
    float rq[2][4] = {{0.f, 0.f, 0.f, 0.f}, {0.f, 0.f, 0.f, 0.f}};
#pragma unroll
    for (int i = 0; i < 2; i++)
#pragma unroll
        for (int j = 0; j < 4; j++) {
            int col = n0 + j * 16 + l16;
            int rbase = m0 + i * 16 + quad * 4;
            float bv = bproj[col];
            float b2v = b2[col];
#pragma unroll
            for (int rr = 0; rr < 4; rr++) {
                int row = rbase + rr;
                float vv = acc[i][j][rr] + bv + xmm[(size_t)row * 1024 + col];
                y[(size_t)row * 1024 + col] = vv;
                outp[(size_t)row * 1024 + col] = vv + b2v;
                rs[i][rr] += vv;
                rq[i][rr] += vv * vv;
            }
        }
#pragma unroll
    for (int i = 0; i < 2; i++)
#pragma unroll
        for (int rr = 0; rr < 4; rr++) {
            float s = rs[i][rr], q = rq[i][rr];
            s += __shfl_xor(s, 1); q += __shfl_xor(q, 1);
            s += __shfl_xor(s, 2); q += __shfl_xor(q, 2);
            s += __shfl_xor(s, 4); q += __shfl_xor(q, 4);
            s += __shfl_xor(s, 8); q += __shfl_xor(q, 8);
            if (l16 == 0) {
                int row = m0 + i * 16 + quad * 4 + rr;
                atomicAdd(&stats[row], s);
                atomicAdd(&stats[512 + row], q);
            }
        }
}

// ---------------------------------------------------------------------------
// mlp1: g = gelu(h0@W1t^T + b1) [512,4096]. 64x64 tiles, 512 blocks, K=1024.
// ---------------------------------------------------------------------------
__global__ __launch_bounds__(64) void mlp1_kernel(
    const ushort_t* __restrict__ h0, const ushort_t* __restrict__ W1t,
    const float* __restrict__ b1, ushort_t* __restrict__ g) {
    int id = blockIdx.x;
    int lane = threadIdx.x;
    int m0 = (id >> 6) * 64, n0 = (id & 63) * 64;
    f32x4 acc[4][4];
#pragma unroll
    for (int i = 0; i < 4; i++)
#pragma unroll
        for (int j = 0; j < 4; j++) acc[i][j] = (f32x4){0.f, 0.f, 0.f, 0.f};
    wave_acc<4, 1024>(h0, 1024, W1t, 1024, m0, n0, lane, acc);

    int quad = lane >> 4, l16 = lane & 15;
#pragma unroll
    for (int i = 0; i < 4; i++)
#pragma unroll
        for (int j = 0; j < 4; j++) {
            int col = n0 + j * 16 + l16;
            int rbase = m0 + i * 16 + quad * 4;
            float bv = b1[col];
#pragma unroll
            for (int rr = 0; rr < 4; rr++) {
                float vv = acc[i][j][rr] + bv;
                vv = 0.5f * vv * (1.f + erff(vv * 0.70710678118654752f));
                g[(size_t)(rbase + rr) * 4096 + col] = f2bf(vv);
            }
        }
}

// ---------------------------------------------------------------------------
// mlp2: outp += g@W2t^T, split-K=4 (grid.y = z), atomicAdd into outp
// (pre-initialized to y + b2 by proj). 64x64 tiles, (128,4) blocks.
// ---------------------------------------------------------------------------
__global__ __launch_bounds__(64) void mlp2_kernel(
    const ushort_t* __restrict__ g, const ushort_t* __restrict__ W2t,
    float* __restrict__ outp) {
    int id = blockIdx.x;
    int z = blockIdx.y;
    int lane = threadIdx.x;
    int m0 = (id >> 4) * 64, n0 = (id & 15) * 64;
    f32x4 acc[4][4];
#pragma unroll
    for (int i = 0; i < 4; i++)
#pragma unroll
        for (int j = 0; j < 4; j++) acc[i][j] = (f32x4){0.f, 0.f, 0.f, 0.f};
    wave_acc<4, 1024>(g + z * 1024, 4096, W2t + z * 1024, 4096, m0, n0, lane,
                      acc);

    int quad = lane >> 4, l16 = lane & 15;
#pragma unroll
    for (int i = 0; i < 4; i++)
#pragma unroll
        for (int j = 0; j < 4; j++) {
            int col = n0 + j * 16 + l16;
            int rbase = m0 + i * 16 + quad * 4;
#pragma unroll
            for (int rr = 0; rr < 4; rr++)
                atomicAdd(&outp[(size_t)(rbase + rr) * 1024 + col],
                          acc[i][j][rr]);
        }
}

// ---------------------------------------------------------------------------
// ln_apply: h0[row] = LN(y[row]) from precomputed stats. 512 x 256.
// ---------------------------------------------------------------------------
__global__ __launch_bounds__(256) void ln_apply(
    const float* __restrict__ y, const float* __restrict__ stats,
    const float* __restrict__ w, const float* __restrict__ b,
    ushort_t* __restrict__ h0) {
    int row = blockIdx.x, tid = threadIdx.x;
    float s = stats[row], ss = stats[512 + row];
    float mean = s * (1.f / 1024.f);
    float rstd = rsqrtf(ss * (1.f / 1024.f) - mean * mean + 1e-5f);
    float4 v4 = ((const float4*)(y + (size_t)row * 1024))[tid];
    float4 w4 = ((const float4*)w)[tid];
    float4 b4 = ((const float4*)b)[tid];
    union { ushort_t u[4]; uint2 v; } pk;
    pk.u[0] = f2bf((v4.x - mean) * rstd * w4.x + b4.x);
    pk.u[1] = f2bf((v4.y - mean) * rstd * w4.y + b4.y);
    pk.u[2] = f2bf((v4.z - mean) * rstd * w4.z + b4.z);
    pk.u[3] = f2bf((v4.w - mean) * rstd * w4.w + b4.w);
    *(uint2*)(h0 + (size_t)row * 1024 + tid * 4) = pk.v;
}

// ---------------------------------------------------------------------------
// Prep: blocks [0,896) = 3 input LayerNorms (fp32 -> bf16);
//       blocks [896, 896+2432) = 5 weight transpose+casts, 64x64 tiles.
//       Block 0 zeroes the stats buffer.
// ---------------------------------------------------------------------------
struct LNSeg {
    const float* x; const float* w; const float* b; ushort_t* out; int start;
};
struct TDesc { const float* in; ushort_t* out; int R, C, nx, start; };

__global__ __launch_bounds__(256) void prep_kernel(LNSeg l0, LNSeg l1,
                                                   LNSeg l2, TDesc d0,
                                                   TDesc d1, TDesc d2,
                                                   TDesc d3, TDesc d4,
                                                   float* stats) {
    int id = blockIdx.x;
    int tid = threadIdx.x;
    if (id == 0) ((float4*)stats)[tid] = (float4){0.f, 0.f, 0.f, 0.f};

    if (id < 896) {
        const float *x, *w, *b; ushort_t* o; int start;
        if (id >= l2.start)      { x = l2.x; w = l2.w; b = l2.b; o = l2.out; start = l2.start; }
        else if (id >= l1.start) { x = l1.x; w = l1.w; b = l1.b; o = l1.out; start = l1.start; }
        else                     { x = l0.x; w = l0.w; b = l0.b; o = l0.out; start = 0; }
        int row = id - start;
        const float4* xr4 = (const float4*)(x + (size_t)row * 1024);
        float4 v4 = xr4[tid];
        float s = v4.x + v4.y + v4.z + v4.w;
        float ss = v4.x * v4.x + v4.y * v4.y + v4.z * v4.z + v4.w * v4.w;
#pragma unroll
        for (int off = 32; off > 0; off >>= 1) {
            s += __shfl_down(s, off);
            ss += __shfl_down(ss, off);
        }
        __shared__ float red[8];
        if ((tid & 63) == 0) {
            red[tid >> 6] = s;
            red[4 + (tid >> 6)] = ss;
        }
        __syncthreads();
        s = red[0] + red[1] + red[2] + red[3];
        ss = red[4] + red[5] + red[6] + red[7];
        float mean = s * (1.f / 1024.f);
        float var = ss * (1.f / 1024.f) - mean * mean;
        float rstd = rsqrtf(var + 1e-5f);
        const float4 w4 = ((const float4*)w)[tid];
        const float4 b4 = ((const float4*)b)[tid];
        union { ushort_t u[4]; uint2 v; } pk;
        pk.u[0] = f2bf((v4.x - mean) * rstd * w4.x + b4.x);
        pk.u[1] = f2bf((v4.y - mean) * rstd * w4.y + b4.y);
        pk.u[2] = f2bf((v4.z - mean) * rstd * w4.z + b4.z);
        pk.u[3] = f2bf((v4.w - mean) * rstd * w4.w + b4.w);
        *(uint2*)(o + (size_t)row * 1024 + tid * 4) = pk.v;
        return;
    }

    int t = id - 896;
    const float* in; ushort_t* out; int R, C, nx, start;
    if (t >= d4.start)      { in = d4.in; out = d4.out; R = d4.R; C = d4.C; nx = d4.nx; start = d4.start; }
    else if (t >= d3.start) { in = d3.in; out = d3.out; R = d3.R; C = d3.C; nx = d3.nx; start = d3.start; }
    else if (t >= d2.start) { in = d2.in; out = d2.out; R = d2.R; C = d2.C; nx = d2.nx; start = d2.start; }
    else if (t >= d1.start) { in = d1.in; out = d1.out; R = d1.R; C = d1.C; nx = d1.nx; start = d1.start; }
    else                    { in = d0.in; out = d0.out; R = d0.R; C = d0.C; nx = d0.nx; start = 0; }
    int tt = t - start;
    int bx = (tt % nx) * 64;
    int by = (tt / nx) * 64;
    __shared__ ushort_t tile[64 * 65];
    int r = tid >> 4, c4 = (tid & 15) * 4;
#pragma unroll
    for (int rr = 0; rr < 4; rr++) {
        int rl = r + rr * 16;
        float4 f = *(const float4*)(in + (size_t)(by + rl) * C + bx + c4);
        ushort_t* tr = tile + rl * 65 + c4;
        tr[0] = f2bf(f.x); tr[1] = f2bf(f.y);
        tr[2] = f2bf(f.z); tr[3] = f2bf(f.w);
    }
    __syncthreads();
#pragma unroll
    for (int rr = 0; rr < 4; rr++) {
        int orow = r + rr * 16;  // row in `out` within tile (col of in)
        union { ushort_t u[4]; uint2 v; } pk;
#pragma unroll
        for (int j = 0; j < 4; j++) pk.u[j] = tile[(c4 + j) * 65 + orow];
        // wait: need out[bx+orow][by + c4..+3] = in[by+c4+j][bx+orow]
        *(uint2*)(out + (size_t)(bx + orow) * R + by + c4) = pk.v;
    }
}

// ---------------------------------------------------------------------------
// Factorized attention. Block = 256 threads: 64 q-rows x 4 dim-groups.
// grid (B*H=32, 4 q-chunks). Single-pass softmax (|s| bounded, no overflow).
// ---------------------------------------------------------------------------
__global__ __launch_bounds__(256) void attn_kernel(
    const ushort_t* __restrict__ q, const ushort_t* __restrict__ kvv,
    const ushort_t* __restrict__ kva, ushort_t* __restrict__ out) {
    int bh = blockIdx.x;
    int b = bh >> 4, h = bh & 15;
    int tid = threadIdx.x;

    __shared__ float Kv[64][16], Vv[64][16], Ka[128][16], Va[128][16];
    {
        int row = tid >> 2, seg = (tid >> 1) & 1, half = tid & 1;
        const ushort_t* src =
            kvv + (size_t)(b * 64 + row) * 512 + seg * 256 + h * 16 + half * 8;
        float* dst = (seg ? Vv[row] : Kv[row]) + half * 8;
        unpack8(*(const uint4*)src, dst);
    }
#pragma unroll
    for (int t2 = 0; t2 < 2; t2++) {
        int t = tid + t2 * 256;
        int row = t >> 2, seg = (t >> 1) & 1, half = t & 1;
        const ushort_t* src =
            kva + (size_t)(b * 128 + row) * 512 + seg * 256 + h * 16 + half * 8;
        float* dst = (seg ? Va[row] : Ka[row]) + half * 8;
        unpack8(*(const uint4*)src, dst);
    }
    __syncthreads();

    int qlocal = tid >> 2;
    int dg = tid & 3;
    int qrow = blockIdx.y * 64 + qlocal;
    const ushort_t* qp = q + (size_t)(b * 256 + qrow) * 256 + h * 16 + dg * 4;
    uint2 qu = *(const uint2*)qp;
    float4 qv;
    qv.x = __uint_as_float(qu.x << 16) * 0.125f;
    qv.y = __uint_as_float(qu.x & 0xFFFF0000u) * 0.125f;
    qv.z = __uint_as_float(qu.y << 16) * 0.125f;
    qv.w = __uint_as_float(qu.y & 0xFFFF0000u) * 0.125f;

    const float4* Kv4 = (const float4*)Kv;
    const float4* Vv4 = (const float4*)Vv;
    const float4* Ka4 = (const float4*)Ka;
    const float4* Va4 = (const float4*)Va;

    float4 ov = {0.f, 0.f, 0.f, 0.f};
    float den = 0.f;
#pragma unroll 8
    for (int i = 0; i < 64; i++) {
        float4 kk = Kv4[i * 4 + dg];
        float part = qv.x * kk.x + qv.y * kk.y + qv.z * kk.z + qv.w * kk.w;
        part += __shfl_xor(part, 1);
        part += __shfl_xor(part, 2);
        float pe = __expf(part);
        den += pe;
        float4 vv = Vv4[i * 4 + dg];
        ov.x += pe * vv.x; ov.y += pe * vv.y;
        ov.z += pe * vv.z; ov.w += pe * vv.w;
    }
    float4 oa = {0.f, 0.f, 0.f, 0.f};
    float dena = 0.f;
#pragma unroll 8
    for (int i = 0; i < 128; i++) {
        float4 kk = Ka4[i * 4 + dg];
        float part = qv.x * kk.x + qv.y * kk.y + qv.z * kk.z + qv.w * kk.w;
        part += __shfl_xor(part, 1);
        part += __shfl_xor(part, 2);
        float pe = __expf(part);
        dena += pe;
        float4 vv = Va4[i * 4 + dg];
        oa.x += pe * vv.x; oa.y += pe * vv.y;
        oa.z += pe * vv.z; oa.w += pe * vv.w;
    }

    float rv = 1.f / den, ra = 1.f / dena;
    union { ushort_t u[4]; uint2 v; } pk;
    pk.u[0] = f2bf(ov.x * rv + oa.x * ra);
    pk.u[1] = f2bf(ov.y * rv + oa.y * ra);
    pk.u[2] = f2bf(ov.z * rv + oa.z * ra);
    pk.u[3] = f2bf(ov.w * rv + oa.w * ra);
    *(uint2*)(out + (size_t)(b * 256 + qrow) * 256 + h * 16 + dg * 4) = pk.v;
}

// ---------------------------------------------------------------------------
extern "C" void kernel_launch(void* const* d_in, const int* in_sizes, int n_in,
                              void* d_out, int out_size, void* d_ws,
                              size_t ws_size, hipStream_t stream) {
    const float* xmm = (const float*)d_in[0];
    const float* xv = (const float*)d_in[1];
    const float* xa = (const float*)d_in[2];
    const float* ln_mm_w = (const float*)d_in[3];
    const float* ln_mm_b = (const float*)d_in[4];
    const float* ln_v_w = (const float*)d_in[5];
    const float* ln_v_b = (const float*)d_in[6];
    const float* ln_a_w = (const float*)d_in[7];
    const float* ln_a_b = (const float*)d_in[8];
    const float* Wq = (const float*)d_in[9];
    const float* Wkv = (const float*)d_in[10];
    const float* Wproj = (const float*)d_in[11];
    const float* bproj = (const float*)d_in[12];
    const float* ln_mlp_w = (const float*)d_in[13];
    const float* ln_mlp_b = (const float*)d_in[14];
    const float* W1 = (const float*)d_in[15];
    const float* b1 = (const float*)d_in[16];
    const float* W2 = (const float*)d_in[17];
    const float* b2 = (const float*)d_in[18];
    float* outp = (float*)d_out;

    char* w = (char*)d_ws;
    ushort_t* xmmN = (ushort_t*)w;    w += 512 * 1024 * 2;
    ushort_t* xvN = (ushort_t*)w;     w += 128 * 1024 * 2;
    ushort_t* xaN = (ushort_t*)w;     w += 256 * 1024 * 2;
    ushort_t* Wqt = (ushort_t*)w;     w += 256 * 1024 * 2;
    ushort_t* Wkvt = (ushort_t*)w;    w += 512 * 2048 * 2;
    ushort_t* Wprojt = (ushort_t*)w;  w += 1024 * 256 * 2;
    ushort_t* W1t = (ushort_t*)w;     w += 4096 * 1024 * 2;
    ushort_t* W2t = (ushort_t*)w;     w += 1024 * 4096 * 2;
    ushort_t* qout = (ushort_t*)w;    w += 512 * 256 * 2;
    ushort_t* kvvb = (ushort_t*)w;    w += 128 * 512 * 2;
    ushort_t* kvab = (ushort_t*)w;    w += 256 * 512 * 2;
    ushort_t* attnout = (ushort_t*)w; w += 512 * 256 * 2;
    float* y = (float*)w;             w += 512 * 1024 * 4;
    ushort_t* h0 = (ushort_t*)w;      w += 512 * 1024 * 2;
    ushort_t* g = (ushort_t*)w;       w += 512 * 4096 * 2;
    float* stats = (float*)w;         w += 1024 * 4;

    // 1) prep: 3 LNs + 5 transposes (64x64 tiles) + zero stats
    LNSeg L0{xmm, ln_mm_w, ln_mm_b, xmmN, 0};
    LNSeg L1{xv, ln_v_w, ln_v_b, xvN, 512};
    LNSeg L2{xa, ln_a_w, ln_a_b, xaN, 640};
    TDesc T0{Wq, Wqt, 1024, 256, 4, 0};        // 16x4   = 64 tiles
    TDesc T1{Wkv, Wkvt, 2048, 512, 8, 64};     // 32x8   = 256
    TDesc T2{Wproj, Wprojt, 256, 1024, 16, 320};  // 4x16 = 64
    TDesc T3{W1, W1t, 1024, 4096, 64, 384};    // 16x64  = 1024
    TDesc T4{W2, W2t, 4096, 1024, 16, 1408};   // 64x16  = 1024
    prep_kernel<<<896 + 2432, 256, 0, stream>>>(L0, L1, L2, T0, T1, T2, T3,
                                                T4, stats);

    // 2) qkv projections (160 wave-blocks)
    qkv_kernel<<<160, 64, 0, stream>>>(xmmN, xvN, xaN, Wqt, Wkvt, qout, kvvb,
                                       kvab);

    // 3) factorized attention
    attn_kernel<<<dim3(32, 4), 256, 0, stream>>>(qout, kvvb, kvab, attnout);

    // 4) proj (+ outp init + LN stats), 256 wave-blocks
    proj_kernel<<<256, 64, 0, stream>>>(attnout, Wprojt, bproj, xmm, b2, y,
                                        outp, stats);

    // 5) h0 = LN(y) via precomputed stats
    ln_apply<<<512, 256, 0, stream>>>(y, stats, ln_mlp_w, ln_mlp_b, h0);

    // 6) mlp1: g = gelu(h0 @ W1 + b1), 512 wave-blocks
    mlp1_kernel<<<512, 64, 0, stream>>>(h0, W1t, b1, g);

    // 7) mlp2: split-K=4, atomic accumulate into outp, (128,4) wave-blocks
    mlp2_kernel<<<dim3(128, 4), 64, 0, stream>>>(g, W2t, outp);

    (void)in_sizes; (void)n_in; (void)out_size; (void)ws_size;
}